// Round 9
// baseline (129.675 us; speedup 1.0000x reference)
//
#include <hip/hip_runtime.h>
#include <hip/hip_bf16.h>

#define DIM 768
#define LTOK 1024
#define NBATCH 32
#define KEEP 256

__device__ __forceinline__ float wave_min_f(float v) {
    #pragma unroll
    for (int off = 32; off > 0; off >>= 1) v = fminf(v, __shfl_xor(v, off, 64));
    return v;
}
__device__ __forceinline__ float wave_max_f(float v) {
    #pragma unroll
    for (int off = 32; off > 0; off >>= 1) v = fmaxf(v, __shfl_xor(v, off, 64));
    return v;
}
__device__ __forceinline__ int wave_sum_i(int v) {
    #pragma unroll
    for (int off = 32; off > 0; off >>= 1) v += __shfl_xor(v, off, 64);
    return v;
}

// Correctly-rounded f32 reciprocal robust to any compile flags: compute in
// f64 (error ~1e-16 rel, below f32 rounding granularity), round once to f32.
__device__ __forceinline__ float recip_cr_f32(float b) {
    return (float)(1.0 / (double)b);
}

// One wave per (n,l) row of 768 f32.
// Hypothesis gamma-1: the np golden ref hoists the broadcast divide as a
// reciprocal-multiply (the idiomatic numpy optimization):
//   inv  = RN32(1 / den)                  [one rounding]
//   nrm  = RN32(s * inv)                  [second rounding]
//   t    = RN32(nrm * 9)                  [third rounding]
//   q    = floor(t) clamped to 0..9       [nrm may reach 1+1ulp or 1-1ulp]
// This chain differs from correctly-rounded division by 1 ulp on ~25% of
// elements, flipping a ~30-element boundary subset DISJOINT from all five
// previously-tested chains — explaining the error pinned at exactly 40.
__global__ __launch_bounds__(256) void ent_kernel(const float* __restrict__ x,
                                                  double* __restrict__ ent) {
    int wid  = blockIdx.x * 4 + (threadIdx.x >> 6);   // row id, 0..32767
    int lane = threadIdx.x & 63;
    const float* row = x + (size_t)wid * DIM;

    float4 a = *(const float4*)(row + lane * 4);
    float4 b = *(const float4*)(row + 256 + lane * 4);
    float4 c = *(const float4*)(row + 512 + lane * 4);

    float mn = fminf(fminf(fminf(a.x, a.y), fminf(a.z, a.w)),
               fminf(fminf(fminf(b.x, b.y), fminf(b.z, b.w)),
                     fminf(fminf(c.x, c.y), fminf(c.z, c.w))));
    float mx = fmaxf(fmaxf(fmaxf(a.x, a.y), fmaxf(a.z, a.w)),
               fmaxf(fmaxf(fmaxf(b.x, b.y), fmaxf(b.z, b.w)),
                     fmaxf(fmaxf(c.x, c.y), fmaxf(c.z, c.w))));
    mn = wave_min_f(mn);
    mx = wave_max_f(mx);

    float den = (mx - mn) + 1e-19f;     // 1e-19 absorbed
    float inv = recip_cr_f32(den);      // RN32(1/den)

    int c0=0,c1=0,c2=0,c3=0,c4=0,c5=0,c6=0,c7=0,c8=0,c9=0;
    #define ACC(v) do { float s_  = (v) - mn;                              \
                        float nr_ = s_ * inv;      /* RN32, lone mul */    \
                        float t_  = nr_ * 9.0f;    /* RN32, lone mul */    \
                        int q = (int)floorf(t_);                           \
                        q = q < 0 ? 0 : (q > 9 ? 9 : q);                   \
                        c0 += (q==0); c1 += (q==1); c2 += (q==2);          \
                        c3 += (q==3); c4 += (q==4); c5 += (q==5);          \
                        c6 += (q==6); c7 += (q==7); c8 += (q==8);          \
                        c9 += (q==9); } while (0)
    ACC(a.x); ACC(a.y); ACC(a.z); ACC(a.w);
    ACC(b.x); ACC(b.y); ACC(b.z); ACC(b.w);
    ACC(c.x); ACC(c.y); ACC(c.z); ACC(c.w);
    #undef ACC

    c0 = wave_sum_i(c0); c1 = wave_sum_i(c1); c2 = wave_sum_i(c2);
    c3 = wave_sum_i(c3); c4 = wave_sum_i(c4); c5 = wave_sum_i(c5);
    c6 = wave_sum_i(c6); c7 = wave_sum_i(c7); c8 = wave_sum_i(c8);
    c9 = wave_sum_i(c9);

    if (lane == 0) {
        #define TERM(cc) ((double)(cc) / 768.0) * log(((double)(cc) / 768.0) + 1e-9)
        double t0 = TERM(c0), t1 = TERM(c1), t2 = TERM(c2), t3 = TERM(c3);
        double t4 = TERM(c4), t5 = TERM(c5), t6 = TERM(c6), t7 = TERM(c7);
        double t8 = TERM(c8), t9 = TERM(c9);
        #undef TERM
        // numpy pairwise order for n=10: tree over first 8, then +t8, +t9
        double s = ((t0 + t1) + (t2 + t3)) + ((t4 + t5) + (t6 + t7));
        s += t8;
        s += t9;
        ent[wid] = -s;
    }
}

// rank(l) = #{j : e_j > e_l} + #{j < l : e_j == e_l}
//         = position of token l in stable argsort(-entropy)  (== ids_restore)
__global__ __launch_bounds__(128) void rank_kernel(const double* __restrict__ ent,
                                                   int* __restrict__ keep,
                                                   float* __restrict__ out_mask,
                                                   float* __restrict__ out_restore) {
    __shared__ double se[LTOK];
    int n = blockIdx.x;      // 0..31
    int chunk = blockIdx.y;  // 0..7
    for (int i = threadIdx.x; i < LTOK; i += 128)
        se[i] = ent[n * LTOK + i];
    __syncthreads();

    int l = chunk * 128 + threadIdx.x;
    double e = se[l];
    int rank = 0;
    #pragma unroll 8
    for (int j = 0; j < LTOK; ++j) {
        double ej = se[j];
        rank += (int)((ej > e) | ((ej == e) & (j < l)));
    }
    out_restore[n * LTOK + l] = (float)rank;
    out_mask[n * LTOK + l]    = (rank < KEEP) ? 0.0f : 1.0f;
    if (rank < KEEP) keep[n * KEEP + rank] = l;   // ids_shuffle[rank] = l
}

// One wave per kept row: x_masked[n, r, :] = x[n, keep[n,r], :]  (f32 copy)
__global__ __launch_bounds__(256) void gather_kernel(const float* __restrict__ x,
                                                     const int* __restrict__ keep,
                                                     float* __restrict__ xm) {
    int r    = blockIdx.x * 4 + (threadIdx.x >> 6);  // 0..8191
    int lane = threadIdx.x & 63;
    int n = r >> 8;
    int k = r & 255;
    int src = keep[n * KEEP + k];
    const float* srow = x + ((size_t)n * LTOK + (size_t)src) * DIM;
    float* drow = xm + (size_t)r * DIM;
    #pragma unroll
    for (int t = 0; t < 3; ++t) {
        float4 v = *(const float4*)(srow + t * 256 + lane * 4);
        *(float4*)(drow + t * 256 + lane * 4) = v;
    }
}

extern "C" void kernel_launch(void* const* d_in, const int* in_sizes, int n_in,
                              void* d_out, int out_size, void* d_ws, size_t ws_size,
                              hipStream_t stream) {
    const float* x = (const float*)d_in[0];

    // d_out is float32, outputs concatenated flat: x_masked | mask | ids_restore
    float* out = (float*)d_out;
    float* out_xm      = out;                                   // 32*256*768
    float* out_mask    = out + (size_t)NBATCH * KEEP * DIM;     // 32*1024
    float* out_restore = out_mask + (size_t)NBATCH * LTOK;      // 32*1024

    double* ws_ent  = (double*)d_ws;                            // 32768 f64
    int*    ws_keep = (int*)((char*)d_ws + (size_t)NBATCH * LTOK * sizeof(double)); // 32*256 i32

    ent_kernel<<<dim3(NBATCH * LTOK / 4), 256, 0, stream>>>(x, ws_ent);
    rank_kernel<<<dim3(NBATCH, 8), 128, 0, stream>>>(ws_ent, ws_keep, out_mask, out_restore);
    gather_kernel<<<dim3(NBATCH * KEEP / 4), 256, 0, stream>>>(x, ws_keep, out_xm);
}

// Round 10
// 68.024 us; speedup vs baseline: 1.9063x; 1.9063x over previous
//
#include <hip/hip_runtime.h>
#include <hip/hip_bf16.h>

#define DIM 768
#define LTOK 1024
#define NBATCH 32
#define KEEP 256

__device__ __forceinline__ float wave_min_f(float v) {
    #pragma unroll
    for (int off = 32; off > 0; off >>= 1) v = fminf(v, __shfl_xor(v, off, 64));
    return v;
}
__device__ __forceinline__ float wave_max_f(float v) {
    #pragma unroll
    for (int off = 32; off > 0; off >>= 1) v = fmaxf(v, __shfl_xor(v, off, 64));
    return v;
}

// Correctly-rounded f32 reciprocal robust to compile flags (matches np's
// hoisted `inv = 1/den` reciprocal-multiply chain, proven in R9).
__device__ __forceinline__ float recip_cr_f32(float b) {
    return (float)(1.0 / (double)b);
}

// term[c] = (c/768)*log(c/768 + 1e-9) in f64 — same expression/ops as the
// R9 in-kernel TERM, so entropy values are bit-identical.
__global__ __launch_bounds__(256) void table_kernel(double* __restrict__ term) {
    int i = blockIdx.x * 256 + threadIdx.x;
    if (i <= DIM) {
        double p = (double)i / 768.0;
        term[i] = p * log(p + 1e-9);
    }
}

// One wave per (n,l) row of 768 f32.
// Matched binning chain (DO NOT TOUCH — R9-verified np semantics):
//   den = (mx-mn)+1e-19f ; inv = RN32(1/den) ; nrm = RN32(s*inv) ;
//   t = RN32(nrm*9) ; q = floor(t) clamped to 9.
// Histogram: per-lane counts (<=12) packed 10x6 bits in one u64
// (acc += 1<<(6q), ~8 instrs/elem vs ~26 for 10x cmp+add), widened once to
// two 12-bit-packed u64 (fields <= 768 < 4096), 6-level butterfly reduce.
// Entropy: 10 table loads + numpy-pairwise f64 adds (no logs in this kernel).
__global__ __launch_bounds__(256) void ent_kernel(const float* __restrict__ x,
                                                  const double* __restrict__ term,
                                                  double* __restrict__ ent) {
    int wid  = blockIdx.x * 4 + (threadIdx.x >> 6);   // row id, 0..32767
    int lane = threadIdx.x & 63;
    const float* row = x + (size_t)wid * DIM;

    float4 a = *(const float4*)(row + lane * 4);
    float4 b = *(const float4*)(row + 256 + lane * 4);
    float4 c = *(const float4*)(row + 512 + lane * 4);

    float mn = fminf(fminf(fminf(a.x, a.y), fminf(a.z, a.w)),
               fminf(fminf(fminf(b.x, b.y), fminf(b.z, b.w)),
                     fminf(fminf(c.x, c.y), fminf(c.z, c.w))));
    float mx = fmaxf(fmaxf(fmaxf(a.x, a.y), fmaxf(a.z, a.w)),
               fmaxf(fmaxf(fmaxf(b.x, b.y), fmaxf(b.z, b.w)),
                     fmaxf(fmaxf(c.x, c.y), fmaxf(c.z, c.w))));
    mn = wave_min_f(mn);
    mx = wave_max_f(mx);

    float den = (mx - mn) + 1e-19f;     // 1e-19 absorbed
    float inv = recip_cr_f32(den);      // RN32(1/den)

    unsigned long long pk = 0ull;       // 10 bins x 6 bits; per-lane max 12
    #define ACC(v) do { float s_  = (v) - mn;                              \
                        float nr_ = s_ * inv;      /* RN32, lone mul */    \
                        float t_  = nr_ * 9.0f;    /* RN32, lone mul */    \
                        int q = (int)floorf(t_);   /* 0..9 (+eps) */       \
                        q = q > 9 ? 9 : q;                                 \
                        pk += 1ull << (6 * q); } while (0)
    ACC(a.x); ACC(a.y); ACC(a.z); ACC(a.w);
    ACC(b.x); ACC(b.y); ACC(b.z); ACC(b.w);
    ACC(c.x); ACC(c.y); ACC(c.z); ACC(c.w);
    #undef ACC

    // widen: bins 0-4 -> lo (12-bit fields), bins 5-9 -> hi
    unsigned long long lo = 0ull, hi = 0ull;
    #pragma unroll
    for (int i = 0; i < 5; ++i) {
        lo |= ((pk >> (6 * i)) & 63ull) << (12 * i);
        hi |= ((pk >> (6 * (i + 5))) & 63ull) << (12 * i);
    }
    #pragma unroll
    for (int off = 32; off > 0; off >>= 1) {
        lo += __shfl_xor(lo, off, 64);
        hi += __shfl_xor(hi, off, 64);
    }

    if (lane == 0) {
        double t0 = term[(lo      ) & 4095ull];
        double t1 = term[(lo >> 12) & 4095ull];
        double t2 = term[(lo >> 24) & 4095ull];
        double t3 = term[(lo >> 36) & 4095ull];
        double t4 = term[(lo >> 48) & 4095ull];
        double t5 = term[(hi      ) & 4095ull];
        double t6 = term[(hi >> 12) & 4095ull];
        double t7 = term[(hi >> 24) & 4095ull];
        double t8 = term[(hi >> 36) & 4095ull];
        double t9 = term[(hi >> 48) & 4095ull];
        // numpy pairwise order for n=10: tree over first 8, then +t8, +t9
        double s = ((t0 + t1) + (t2 + t3)) + ((t4 + t5) + (t6 + t7));
        s += t8;
        s += t9;
        ent[wid] = -s;
    }
}

// rank(l) = #{j : e_j > e_l} + #{j < l : e_j == e_l}  (== ids_restore)
__global__ __launch_bounds__(128) void rank_kernel(const double* __restrict__ ent,
                                                   int* __restrict__ keep,
                                                   float* __restrict__ out_mask,
                                                   float* __restrict__ out_restore) {
    __shared__ double se[LTOK];
    int n = blockIdx.x;      // 0..31
    int chunk = blockIdx.y;  // 0..7
    for (int i = threadIdx.x; i < LTOK; i += 128)
        se[i] = ent[n * LTOK + i];
    __syncthreads();

    int l = chunk * 128 + threadIdx.x;
    double e = se[l];
    int rank = 0;
    #pragma unroll 8
    for (int j = 0; j < LTOK; ++j) {
        double ej = se[j];
        rank += (int)((ej > e) | ((ej == e) & (j < l)));
    }
    out_restore[n * LTOK + l] = (float)rank;
    out_mask[n * LTOK + l]    = (rank < KEEP) ? 0.0f : 1.0f;
    if (rank < KEEP) keep[n * KEEP + rank] = l;   // ids_shuffle[rank] = l
}

// One wave per kept row: x_masked[n, r, :] = x[n, keep[n,r], :]  (f32 copy)
__global__ __launch_bounds__(256) void gather_kernel(const float* __restrict__ x,
                                                     const int* __restrict__ keep,
                                                     float* __restrict__ xm) {
    int r    = blockIdx.x * 4 + (threadIdx.x >> 6);  // 0..8191
    int lane = threadIdx.x & 63;
    int n = r >> 8;
    int k = r & 255;
    int src = keep[n * KEEP + k];
    const float* srow = x + ((size_t)n * LTOK + (size_t)src) * DIM;
    float* drow = xm + (size_t)r * DIM;
    #pragma unroll
    for (int t = 0; t < 3; ++t) {
        float4 v = *(const float4*)(srow + t * 256 + lane * 4);
        *(float4*)(drow + t * 256 + lane * 4) = v;
    }
}

extern "C" void kernel_launch(void* const* d_in, const int* in_sizes, int n_in,
                              void* d_out, int out_size, void* d_ws, size_t ws_size,
                              hipStream_t stream) {
    const float* x = (const float*)d_in[0];

    // d_out is float32, outputs concatenated flat: x_masked | mask | ids_restore
    float* out = (float*)d_out;
    float* out_xm      = out;                                   // 32*256*768
    float* out_mask    = out + (size_t)NBATCH * KEEP * DIM;     // 32*1024
    float* out_restore = out_mask + (size_t)NBATCH * LTOK;      // 32*1024

    // ws layout: term table (769 f64, padded to 8 KiB) | ent (32768 f64) | keep
    double* ws_term = (double*)d_ws;
    double* ws_ent  = (double*)((char*)d_ws + 8192);
    int*    ws_keep = (int*)((char*)d_ws + 8192 + (size_t)NBATCH * LTOK * sizeof(double));

    table_kernel<<<dim3(4), 256, 0, stream>>>(ws_term);
    ent_kernel<<<dim3(NBATCH * LTOK / 4), 256, 0, stream>>>(x, ws_term, ws_ent);
    rank_kernel<<<dim3(NBATCH, 8), 128, 0, stream>>>(ws_ent, ws_keep, out_mask, out_restore);
    gather_kernel<<<dim3(NBATCH * KEEP / 4), 256, 0, stream>>>(x, ws_keep, out_xm);
}

// Round 11
// 65.389 us; speedup vs baseline: 1.9831x; 1.0403x over previous
//
#include <hip/hip_runtime.h>
#include <hip/hip_bf16.h>

#define DIM 768
#define LTOK 1024
#define NBATCH 32
#define KEEP 256

// Correctly-rounded f32 reciprocal robust to compile flags (matches np's
// hoisted `inv = 1/den` reciprocal-multiply chain, proven in R9).
__device__ __forceinline__ float recip_cr_f32(float b) {
    return (float)(1.0 / (double)b);
}

// term[c] = (c/768)*log(c/768 + 1e-9) in f64 — same expression/ops as the
// R9 in-kernel TERM, so entropy values are bit-identical.
__global__ __launch_bounds__(256) void table_kernel(double* __restrict__ term) {
    int i = blockIdx.x * 256 + threadIdx.x;
    if (i <= DIM) {
        double p = (double)i / 768.0;
        term[i] = p * log(p + 1e-9);
    }
}

// TWO rows per wave: lanes 0-31 -> row wid, lanes 32-63 -> row wid+1.
// Per lane: 24 elements (6 float4), binned with the R9-verified np chain:
//   den = (mx-mn)+1e-19f ; inv = RN32(1/den) ; nrm = RN32(s*inv) ;
//   t = RN32(nrm*9) ; q = (int)t   [trunc == floor: t>=0; q<=9 provable]
// Histogram: u64 10x6-bit pack (per-lane count <=24; one pre-widen butterfly
// level sums <=48 < 63), widen to 2x u64 12-bit fields, 4-level butterfly.
// Entropy: 10 f64 table loads + numpy pairwise-order adds (no logs here).
__global__ __launch_bounds__(256) void ent_kernel(const float* __restrict__ x,
                                                  const double* __restrict__ term,
                                                  double* __restrict__ ent) {
    int wave = blockIdx.x * 4 + (threadIdx.x >> 6);   // 0..16383
    int wid  = wave * 2;                              // first of 2 rows
    int lane = threadIdx.x & 63;
    int g    = lane >> 5;                             // 0: row wid, 1: wid+1
    int il   = lane & 31;
    const float* row = x + (size_t)(wid + g) * DIM;

    float4 v0 = *(const float4*)(row + il * 4);
    float4 v1 = *(const float4*)(row + il * 4 + 128);
    float4 v2 = *(const float4*)(row + il * 4 + 256);
    float4 v3 = *(const float4*)(row + il * 4 + 384);
    float4 v4 = *(const float4*)(row + il * 4 + 512);
    float4 v5 = *(const float4*)(row + il * 4 + 640);

    // left-chains fuse to v_min3/v_max3 on gfx950
    float mn = v0.x;
    mn = fminf(mn, v0.y); mn = fminf(mn, v0.z); mn = fminf(mn, v0.w);
    mn = fminf(mn, v1.x); mn = fminf(mn, v1.y); mn = fminf(mn, v1.z); mn = fminf(mn, v1.w);
    mn = fminf(mn, v2.x); mn = fminf(mn, v2.y); mn = fminf(mn, v2.z); mn = fminf(mn, v2.w);
    mn = fminf(mn, v3.x); mn = fminf(mn, v3.y); mn = fminf(mn, v3.z); mn = fminf(mn, v3.w);
    mn = fminf(mn, v4.x); mn = fminf(mn, v4.y); mn = fminf(mn, v4.z); mn = fminf(mn, v4.w);
    mn = fminf(mn, v5.x); mn = fminf(mn, v5.y); mn = fminf(mn, v5.z); mn = fminf(mn, v5.w);
    float mx = v0.x;
    mx = fmaxf(mx, v0.y); mx = fmaxf(mx, v0.z); mx = fmaxf(mx, v0.w);
    mx = fmaxf(mx, v1.x); mx = fmaxf(mx, v1.y); mx = fmaxf(mx, v1.z); mx = fmaxf(mx, v1.w);
    mx = fmaxf(mx, v2.x); mx = fmaxf(mx, v2.y); mx = fmaxf(mx, v2.z); mx = fmaxf(mx, v2.w);
    mx = fmaxf(mx, v3.x); mx = fmaxf(mx, v3.y); mx = fmaxf(mx, v3.z); mx = fmaxf(mx, v3.w);
    mx = fmaxf(mx, v4.x); mx = fmaxf(mx, v4.y); mx = fmaxf(mx, v4.z); mx = fmaxf(mx, v4.w);
    mx = fmaxf(mx, v5.x); mx = fmaxf(mx, v5.y); mx = fmaxf(mx, v5.z); mx = fmaxf(mx, v5.w);

    // 32-lane butterfly (xor<32 keeps lanes within their half)
    #pragma unroll
    for (int off = 16; off > 0; off >>= 1) {
        mn = fminf(mn, __shfl_xor(mn, off, 64));
        mx = fmaxf(mx, __shfl_xor(mx, off, 64));
    }

    float den = (mx - mn) + 1e-19f;     // 1e-19 absorbed
    float inv = recip_cr_f32(den);      // RN32(1/den)

    unsigned long long pk = 0ull;       // 10 bins x 6 bits; per-lane max 24
    #define ACC(v) do { float s_  = (v) - mn;                              \
                        float nr_ = s_ * inv;      /* RN32, lone mul */    \
                        float t_  = nr_ * 9.0f;    /* RN32, lone mul */    \
                        int q = (int)t_;           /* trunc==floor, 0..9 */\
                        pk += 1ull << (6 * q); } while (0)
    ACC(v0.x); ACC(v0.y); ACC(v0.z); ACC(v0.w);
    ACC(v1.x); ACC(v1.y); ACC(v1.z); ACC(v1.w);
    ACC(v2.x); ACC(v2.y); ACC(v2.z); ACC(v2.w);
    ACC(v3.x); ACC(v3.y); ACC(v3.z); ACC(v3.w);
    ACC(v4.x); ACC(v4.y); ACC(v4.z); ACC(v4.w);
    ACC(v5.x); ACC(v5.y); ACC(v5.z); ACC(v5.w);
    #undef ACC

    // one 6-bit-packed level first (sum <= 48 per field, no overflow)
    pk += __shfl_xor(pk, 1, 64);

    // widen: bins 0-4 -> lo (12-bit fields), bins 5-9 -> hi
    unsigned long long lo = 0ull, hi = 0ull;
    #pragma unroll
    for (int i = 0; i < 5; ++i) {
        lo |= ((pk >> (6 * i)) & 63ull) << (12 * i);
        hi |= ((pk >> (6 * (i + 5))) & 63ull) << (12 * i);
    }
    #pragma unroll
    for (int off = 2; off <= 16; off <<= 1) {
        lo += __shfl_xor(lo, off, 64);
        hi += __shfl_xor(hi, off, 64);
    }

    if (il == 0) {
        double t0 = term[(lo      ) & 4095ull];
        double t1 = term[(lo >> 12) & 4095ull];
        double t2 = term[(lo >> 24) & 4095ull];
        double t3 = term[(lo >> 36) & 4095ull];
        double t4 = term[(lo >> 48) & 4095ull];
        double t5 = term[(hi      ) & 4095ull];
        double t6 = term[(hi >> 12) & 4095ull];
        double t7 = term[(hi >> 24) & 4095ull];
        double t8 = term[(hi >> 36) & 4095ull];
        double t9 = term[(hi >> 48) & 4095ull];
        // numpy pairwise order for n=10: tree over first 8, then +t8, +t9
        double s = ((t0 + t1) + (t2 + t3)) + ((t4 + t5) + (t6 + t7));
        s += t8;
        s += t9;
        ent[wid + g] = -s;
    }
}

// rank(l) = #{j : e_j > e_l} + #{j < l : e_j == e_l}  (== ids_restore)
__global__ __launch_bounds__(128) void rank_kernel(const double* __restrict__ ent,
                                                   int* __restrict__ keep,
                                                   float* __restrict__ out_mask,
                                                   float* __restrict__ out_restore) {
    __shared__ double se[LTOK];
    int n = blockIdx.x;      // 0..31
    int chunk = blockIdx.y;  // 0..7
    for (int i = threadIdx.x; i < LTOK; i += 128)
        se[i] = ent[n * LTOK + i];
    __syncthreads();

    int l = chunk * 128 + threadIdx.x;
    double e = se[l];
    int rank = 0;
    #pragma unroll 8
    for (int j = 0; j < LTOK; ++j) {
        double ej = se[j];
        rank += (int)((ej > e) | ((ej == e) & (j < l)));
    }
    out_restore[n * LTOK + l] = (float)rank;
    out_mask[n * LTOK + l]    = (rank < KEEP) ? 0.0f : 1.0f;
    if (rank < KEEP) keep[n * KEEP + rank] = l;   // ids_shuffle[rank] = l
}

// One wave per kept row: x_masked[n, r, :] = x[n, keep[n,r], :]  (f32 copy)
__global__ __launch_bounds__(256) void gather_kernel(const float* __restrict__ x,
                                                     const int* __restrict__ keep,
                                                     float* __restrict__ xm) {
    int r    = blockIdx.x * 4 + (threadIdx.x >> 6);  // 0..8191
    int lane = threadIdx.x & 63;
    int n = r >> 8;
    int k = r & 255;
    int src = keep[n * KEEP + k];
    const float* srow = x + ((size_t)n * LTOK + (size_t)src) * DIM;
    float* drow = xm + (size_t)r * DIM;
    #pragma unroll
    for (int t = 0; t < 3; ++t) {
        float4 v = *(const float4*)(srow + t * 256 + lane * 4);
        *(float4*)(drow + t * 256 + lane * 4) = v;
    }
}

extern "C" void kernel_launch(void* const* d_in, const int* in_sizes, int n_in,
                              void* d_out, int out_size, void* d_ws, size_t ws_size,
                              hipStream_t stream) {
    const float* x = (const float*)d_in[0];

    // d_out is float32, outputs concatenated flat: x_masked | mask | ids_restore
    float* out = (float*)d_out;
    float* out_xm      = out;                                   // 32*256*768
    float* out_mask    = out + (size_t)NBATCH * KEEP * DIM;     // 32*1024
    float* out_restore = out_mask + (size_t)NBATCH * LTOK;      // 32*1024

    // ws layout: term table (769 f64, padded to 8 KiB) | ent (32768 f64) | keep
    double* ws_term = (double*)d_ws;
    double* ws_ent  = (double*)((char*)d_ws + 8192);
    int*    ws_keep = (int*)((char*)d_ws + 8192 + (size_t)NBATCH * LTOK * sizeof(double));

    table_kernel<<<dim3(4), 256, 0, stream>>>(ws_term);
    ent_kernel<<<dim3(NBATCH * LTOK / 8), 256, 0, stream>>>(x, ws_term, ws_ent);
    rank_kernel<<<dim3(NBATCH, 8), 128, 0, stream>>>(ws_ent, ws_keep, out_mask, out_restore);
    gather_kernel<<<dim3(NBATCH * KEEP / 4), 256, 0, stream>>>(x, ws_keep, out_xm);
}